// Round 2
// baseline (3503.222 us; speedup 1.0000x reference)
//
#include <hip/hip_runtime.h>
#include <cstdint>
#include <cstddef>

// Problem constants (from reference)
#define TOK   16384        // B*S tokens
#define DM    1024         // d_model
#define IM    1024         // intermediate per expert
#define NE    32           // experts
#define TOPK  2
#define CAP   1280         // capacity per expert
#define NSLOT (TOK*TOPK)   // 32768 (token, k) slots

__device__ __forceinline__ float silu_f(float g) {
  return g / (1.f + expf(-g));
}

// ---------------------------------------------------------------------------
// Zero output (re-poisoned to 0xAA before every timed launch) + colsum accum
// ---------------------------------------------------------------------------
__global__ __launch_bounds__(256) void zero_k(float4* __restrict__ out4,
                                              float* __restrict__ colsum) {
  size_t i = (size_t)blockIdx.x * 256 + threadIdx.x;
  out4[i] = make_float4(0.f, 0.f, 0.f, 0.f);
  if (blockIdx.x == 0 && threadIdx.x < NE) colsum[threadIdx.x] = 0.f;
}

// ---------------------------------------------------------------------------
// Router: logits = x @ gw^T, softmax, top-2, renormalized weights.
// One block (256 thr) per token. fp32 throughout (must match ref top-k).
// ---------------------------------------------------------------------------
__global__ __launch_bounds__(256) void router_k(const float* __restrict__ x,
                                                const float* __restrict__ gw,
                                                float* __restrict__ probs,
                                                int* __restrict__ top_e,
                                                float* __restrict__ top_w) {
  const int t = blockIdx.x;
  __shared__ float xs[DM];
  __shared__ float lg[NE];
  __shared__ float ps[NE];
  const int tid = threadIdx.x;

  ((float4*)xs)[tid] = ((const float4*)(x + (size_t)t * DM))[tid];
  __syncthreads();

  const int e = tid >> 3, part = tid & 7;          // 8 threads per expert
  const float* w  = gw + (size_t)e * DM + part * 128;
  const float* xv = xs + part * 128;
  float s = 0.f;
#pragma unroll 8
  for (int j = 0; j < 128; j += 4) {
    float4 wv = *(const float4*)(w + j);
    float4 x4 = *(const float4*)(xv + j);
    s = fmaf(wv.x, x4.x, s); s = fmaf(wv.y, x4.y, s);
    s = fmaf(wv.z, x4.z, s); s = fmaf(wv.w, x4.w, s);
  }
  s += __shfl_xor(s, 4); s += __shfl_xor(s, 2); s += __shfl_xor(s, 1);
  if (part == 0) lg[e] = s;
  __syncthreads();

  if (tid < NE) {
    float v = lg[tid];
    float m = v;
    for (int off = 16; off; off >>= 1) m = fmaxf(m, __shfl_xor(m, off));
    float ex = expf(v - m);
    float sum = ex;
    for (int off = 16; off; off >>= 1) sum += __shfl_xor(sum, off);
    float p = ex / sum;
    probs[(size_t)t * NE + tid] = p;
    ps[tid] = p;
  }
  __syncthreads();

  if (tid == 0) {
    int i0 = 0; float v0 = ps[0];
    for (int j = 1; j < NE; ++j) if (ps[j] > v0) { v0 = ps[j]; i0 = j; }
    int i1 = -1; float v1 = -1.f;
    for (int j = 0; j < NE; ++j) {
      if (j == i0) continue;
      if (ps[j] > v1) { v1 = ps[j]; i1 = j; }
    }
    float inv = 1.f / (v0 + v1 + 1e-9f);
    top_e[t * 2]     = i0;  top_e[t * 2 + 1] = i1;
    top_w[t * 2]     = v0 * inv;
    top_w[t * 2 + 1] = v1 * inv;
  }
}

// ---------------------------------------------------------------------------
// Column-sum of probs (for aux loss): 64 blocks x 256 tokens
// ---------------------------------------------------------------------------
__global__ __launch_bounds__(256) void probsum_k(const float* __restrict__ probs,
                                                 float* __restrict__ colsum) {
  __shared__ float sd[NE];
  const int tid = threadIdx.x;
  if (tid < NE) sd[tid] = 0.f;
  __syncthreads();
  const int e = tid & 31, rg = tid >> 5;
  size_t t0 = (size_t)blockIdx.x * 256 + (size_t)rg * 32;
  float s = 0.f;
  for (int r = 0; r < 32; ++r) s += probs[(t0 + r) * NE + e];
  atomicAdd(&sd[e], s);
  __syncthreads();
  if (tid < NE) atomicAdd(&colsum[tid], sd[tid]);
}

// ---------------------------------------------------------------------------
// Per-chunk stable expert histogram + local ranks. 32 chunks x 1024 slots.
// One wave per block; ballot-based stable ranking within the chunk.
// ---------------------------------------------------------------------------
__global__ __launch_bounds__(64) void hist_k(const int* __restrict__ top_e,
                                             int* __restrict__ pos_local,
                                             int* __restrict__ hist) {
  const int lane = threadIdx.x;
  const unsigned long long lt = (1ull << lane) - 1ull;
  int cnt = 0;                       // lane l holds running count for expert l
  const int base_slot = blockIdx.x * 1024;
  for (int r = 0; r < 16; ++r) {
    int s = base_slot + r * 64 + lane;
    int e = top_e[s];
    int rank = 0;
#pragma unroll
    for (int ex = 0; ex < NE; ++ex) {
      unsigned long long m = __ballot(e == ex);
      int b = __shfl(cnt, ex);
      if (e == ex) rank = b + __popcll(m & lt);
      if (lane == ex) cnt += __popcll(m);
    }
    pos_local[s] = rank;
  }
  if (lane < NE) hist[blockIdx.x * NE + lane] = cnt;
}

// ---------------------------------------------------------------------------
// Scan chunks -> per-chunk expert base, total counts, capped counts
// ---------------------------------------------------------------------------
__global__ void scan_k(const int* __restrict__ hist,
                       int* __restrict__ chunk_base,
                       int* __restrict__ counts,
                       int* __restrict__ ncap) {
  const int e = threadIdx.x;
  if (e >= NE) return;
  int b = 0;
  for (int c = 0; c < 32; ++c) {
    chunk_base[c * NE + e] = b;
    b += hist[c * NE + e];
  }
  counts[e] = b;
  ncap[e] = b < CAP ? b : CAP;
}

// ---------------------------------------------------------------------------
// Build per-expert permutation (row -> token) and weights; drops pos >= CAP
// ---------------------------------------------------------------------------
__global__ __launch_bounds__(256) void scatter_k(const int* __restrict__ top_e,
                                                 const float* __restrict__ top_w,
                                                 const int* __restrict__ pos_local,
                                                 const int* __restrict__ chunk_base,
                                                 int* __restrict__ perm,
                                                 float* __restrict__ wgt) {
  const int s = blockIdx.x * 256 + threadIdx.x;
  const int e = top_e[s];
  const int pos = pos_local[s] + chunk_base[(s >> 10) * NE + e];
  if (pos < CAP) {
    perm[e * CAP + pos] = s >> 1;     // token id (K == 2)
    wgt[e * CAP + pos]  = top_w[s];
  }
}

// ---------------------------------------------------------------------------
// aux = E * sum_e (counts[e]/T * colsum[e]/T)
// ---------------------------------------------------------------------------
__global__ void aux_k(const int* __restrict__ counts,
                      const float* __restrict__ colsum,
                      float* __restrict__ out_aux) {
  const int e = threadIdx.x;
  float v = 0.f;
  if (e < NE) v = ((float)counts[e] / (float)TOK) * (colsum[e] / (float)TOK);
  for (int off = 16; off; off >>= 1) v += __shfl_xor(v, off);
  if (e == 0) out_aux[0] = (float)NE * v;
}

// ---------------------------------------------------------------------------
// FFN GEMM1 fused with SwiGLU: act[e,c,i] = silu(g)*u, g/u from x @ wgu^T.
// 64x64 tile over (rows, I-cols), BK=16, 4x4 micro-tile, gathered A rows.
// ---------------------------------------------------------------------------
__global__ __launch_bounds__(256) void ffn1_k(const float* __restrict__ x,
                                              const float* __restrict__ wgu,
                                              const int* __restrict__ perm,
                                              const int* __restrict__ ncap,
                                              float* __restrict__ act) {
  const int e = blockIdx.z;
  const int ne = ncap[e];
  const int rb = blockIdx.y * 64;
  if (rb >= ne) return;
  const int jb = blockIdx.x * 64;

  __shared__ float As[16][64];
  __shared__ float Bg[16][64];
  __shared__ float Bu[16][64];

  const int tid = threadIdx.x;
  const int lrow = tid >> 2, lq = tid & 3;

  int token = -1;
  if (rb + lrow < ne) token = perm[e * CAP + rb + lrow];
  const bool haveA = token >= 0;
  const float* arow = x + (size_t)(haveA ? token : 0) * DM + lq * 4;
  const float* grow = wgu + ((size_t)e * (2 * IM) + (jb + lrow)) * DM + lq * 4;
  const float* urow = grow + (size_t)IM * DM;

  const int ty = tid >> 4, tx = tid & 15;
  float ag[4][4] = {{0.f}}, au[4][4] = {{0.f}};

  for (int k0 = 0; k0 < DM; k0 += 16) {
    float4 av = make_float4(0.f, 0.f, 0.f, 0.f);
    if (haveA) av = *(const float4*)(arow + k0);
    float4 gv = *(const float4*)(grow + k0);
    float4 uv = *(const float4*)(urow + k0);
    __syncthreads();
    As[lq*4+0][lrow] = av.x; As[lq*4+1][lrow] = av.y;
    As[lq*4+2][lrow] = av.z; As[lq*4+3][lrow] = av.w;
    Bg[lq*4+0][lrow] = gv.x; Bg[lq*4+1][lrow] = gv.y;
    Bg[lq*4+2][lrow] = gv.z; Bg[lq*4+3][lrow] = gv.w;
    Bu[lq*4+0][lrow] = uv.x; Bu[lq*4+1][lrow] = uv.y;
    Bu[lq*4+2][lrow] = uv.z; Bu[lq*4+3][lrow] = uv.w;
    __syncthreads();
#pragma unroll
    for (int kk = 0; kk < 16; ++kk) {
      float4 a4 = *(const float4*)&As[kk][ty * 4];
      float4 g4 = *(const float4*)&Bg[kk][tx * 4];
      float4 u4 = *(const float4*)&Bu[kk][tx * 4];
      float aa[4] = {a4.x, a4.y, a4.z, a4.w};
      float gg[4] = {g4.x, g4.y, g4.z, g4.w};
      float uu[4] = {u4.x, u4.y, u4.z, u4.w};
#pragma unroll
      for (int i2 = 0; i2 < 4; ++i2)
#pragma unroll
        for (int j2 = 0; j2 < 4; ++j2) {
          ag[i2][j2] = fmaf(aa[i2], gg[j2], ag[i2][j2]);
          au[i2][j2] = fmaf(aa[i2], uu[j2], au[i2][j2]);
        }
    }
  }

#pragma unroll
  for (int i2 = 0; i2 < 4; ++i2) {
    const int r = rb + ty * 4 + i2;
    if (r < ne) {
      float4 o;
      o.x = silu_f(ag[i2][0]) * au[i2][0];
      o.y = silu_f(ag[i2][1]) * au[i2][1];
      o.z = silu_f(ag[i2][2]) * au[i2][2];
      o.w = silu_f(ag[i2][3]) * au[i2][3];
      *(float4*)(act + ((size_t)e * CAP + r) * IM + jb + tx * 4) = o;
    }
  }
}

// ---------------------------------------------------------------------------
// FFN GEMM2 fused with weighted scatter-combine:
// out[token] += w * (act @ down^T) via fp32 atomics. 64x64 tile, BK=16.
// ---------------------------------------------------------------------------
__global__ __launch_bounds__(256) void ffn2_k(const float* __restrict__ act,
                                              const float* __restrict__ down,
                                              const int* __restrict__ perm,
                                              const float* __restrict__ wgt,
                                              const int* __restrict__ ncap,
                                              float* __restrict__ out) {
  const int e = blockIdx.z;
  const int ne = ncap[e];
  const int rb = blockIdx.y * 64;
  if (rb >= ne) return;
  const int jb = blockIdx.x * 64;   // column in D

  __shared__ float As[16][64];
  __shared__ float Bs[16][64];

  const int tid = threadIdx.x;
  const int lrow = tid >> 2, lq = tid & 3;
  const bool haveA = (rb + lrow) < ne;
  const float* arow = act + ((size_t)e * CAP + rb + lrow) * IM + lq * 4;
  const float* brow = down + ((size_t)e * DM + jb + lrow) * IM + lq * 4;

  const int ty = tid >> 4, tx = tid & 15;
  float acc[4][4] = {{0.f}};

  for (int k0 = 0; k0 < IM; k0 += 16) {
    float4 av = make_float4(0.f, 0.f, 0.f, 0.f);
    if (haveA) av = *(const float4*)(arow + k0);
    float4 bv = *(const float4*)(brow + k0);
    __syncthreads();
    As[lq*4+0][lrow] = av.x; As[lq*4+1][lrow] = av.y;
    As[lq*4+2][lrow] = av.z; As[lq*4+3][lrow] = av.w;
    Bs[lq*4+0][lrow] = bv.x; Bs[lq*4+1][lrow] = bv.y;
    Bs[lq*4+2][lrow] = bv.z; Bs[lq*4+3][lrow] = bv.w;
    __syncthreads();
#pragma unroll
    for (int kk = 0; kk < 16; ++kk) {
      float4 a4 = *(const float4*)&As[kk][ty * 4];
      float4 b4 = *(const float4*)&Bs[kk][tx * 4];
      float aa[4] = {a4.x, a4.y, a4.z, a4.w};
      float bb[4] = {b4.x, b4.y, b4.z, b4.w};
#pragma unroll
      for (int i2 = 0; i2 < 4; ++i2)
#pragma unroll
        for (int j2 = 0; j2 < 4; ++j2)
          acc[i2][j2] = fmaf(aa[i2], bb[j2], acc[i2][j2]);
    }
  }

#pragma unroll
  for (int i2 = 0; i2 < 4; ++i2) {
    const int r = rb + ty * 4 + i2;
    if (r < ne) {
      const int token = perm[e * CAP + r];
      const float w = wgt[e * CAP + r];
      float* dst = out + (size_t)token * DM + jb + tx * 4;
      atomicAdd(dst + 0, w * acc[i2][0]);
      atomicAdd(dst + 1, w * acc[i2][1]);
      atomicAdd(dst + 2, w * acc[i2][2]);
      atomicAdd(dst + 3, w * acc[i2][3]);
    }
  }
}

// ---------------------------------------------------------------------------
extern "C" void kernel_launch(void* const* d_in, const int* in_sizes, int n_in,
                              void* d_out, int out_size, void* d_ws, size_t ws_size,
                              hipStream_t stream) {
  const float* x   = (const float*)d_in[0];
  const float* gw  = (const float*)d_in[1];
  const float* wgu = (const float*)d_in[2];
  const float* wdn = (const float*)d_in[3];
  float* out = (float*)d_out;

  char* p = (char*)d_ws;
  auto alloc = [&](size_t bytes) {
    char* r = p;
    p += (bytes + 255) & ~(size_t)255;
    return r;
  };
  float* probs      = (float*)alloc((size_t)TOK * NE * 4);
  int*   top_e      = (int*)  alloc((size_t)NSLOT * 4);
  float* top_w      = (float*)alloc((size_t)NSLOT * 4);
  int*   pos_local  = (int*)  alloc((size_t)NSLOT * 4);
  int*   hist       = (int*)  alloc(32 * NE * 4);
  int*   chunk_base = (int*)  alloc(32 * NE * 4);
  int*   counts     = (int*)  alloc(NE * 4);
  int*   ncapv      = (int*)  alloc(NE * 4);
  float* colsum     = (float*)alloc(NE * 4);
  int*   perm       = (int*)  alloc((size_t)NE * CAP * 4);
  float* wgt        = (float*)alloc((size_t)NE * CAP * 4);
  float* act        = (float*)alloc((size_t)NE * CAP * IM * 4);

  zero_k<<<(TOK * DM) / 1024, 256, 0, stream>>>((float4*)out, colsum);
  router_k<<<TOK, 256, 0, stream>>>(x, gw, probs, top_e, top_w);
  probsum_k<<<64, 256, 0, stream>>>(probs, colsum);
  hist_k<<<32, 64, 0, stream>>>(top_e, pos_local, hist);
  scan_k<<<1, 32, 0, stream>>>(hist, chunk_base, counts, ncapv);
  scatter_k<<<NSLOT / 256, 256, 0, stream>>>(top_e, top_w, pos_local, chunk_base,
                                             perm, wgt);
  aux_k<<<1, 64, 0, stream>>>(counts, colsum, out + (size_t)TOK * DM);
  ffn1_k<<<dim3(IM / 64, CAP / 64, NE), 256, 0, stream>>>(x, wgu, perm, ncapv, act);
  ffn2_k<<<dim3(DM / 64, CAP / 64, NE), 256, 0, stream>>>(act, wdn, perm, wgt,
                                                          ncapv, out);
}

// Round 3
// 1101.959 us; speedup vs baseline: 3.1791x; 3.1791x over previous
//
#include <hip/hip_runtime.h>
#include <cstdint>
#include <cstddef>

// Problem constants (from reference)
#define TOK   16384        // B*S tokens
#define DM    1024         // d_model
#define IM    1024         // intermediate per expert
#define NE    32           // experts
#define CAP   1280         // capacity per expert
#define NSLOT (TOK*2)      // 32768 (token, k) slots

typedef __attribute__((ext_vector_type(8))) short bf16x8;   // 8 bf16 (4 VGPRs)
typedef __attribute__((ext_vector_type(4))) float f32x4;    // MFMA C/D

__device__ __forceinline__ float silu_f(float g) {
  return g / (1.f + expf(-g));
}

__device__ __forceinline__ unsigned short f2bf(float f) {   // RNE fp32->bf16
  unsigned int u = __float_as_uint(f);
  return (unsigned short)((u + 0x7FFFu + ((u >> 16) & 1u)) >> 16);
}

// async global->LDS, 16B per lane; LDS dest wave-uniform base + lane*16
__device__ __forceinline__ void gload16(const void* g, void* l) {
  __builtin_amdgcn_global_load_lds((const __attribute__((address_space(1))) void*)g,
                                   (__attribute__((address_space(3))) void*)l,
                                   16, 0, 0);
}

// ---------------------------------------------------------------------------
// Zero output + colsum
// ---------------------------------------------------------------------------
__global__ __launch_bounds__(256) void zero_k(float4* __restrict__ out4,
                                              float* __restrict__ colsum) {
  size_t i = (size_t)blockIdx.x * 256 + threadIdx.x;
  out4[i] = make_float4(0.f, 0.f, 0.f, 0.f);
  if (blockIdx.x == 0 && threadIdx.x < NE) colsum[threadIdx.x] = 0.f;
}

// ---------------------------------------------------------------------------
// fp32 -> bf16 cast, 8 elems/thread
// ---------------------------------------------------------------------------
__global__ __launch_bounds__(256) void cast_k(const float* __restrict__ in,
                                              unsigned short* __restrict__ out) {
  size_t i = ((size_t)blockIdx.x * 256 + threadIdx.x) * 8;
  const float4 a = *(const float4*)(in + i);
  const float4 b = *(const float4*)(in + i + 4);
  union { unsigned short s[8]; uint4 v; } u;
  u.s[0] = f2bf(a.x); u.s[1] = f2bf(a.y); u.s[2] = f2bf(a.z); u.s[3] = f2bf(a.w);
  u.s[4] = f2bf(b.x); u.s[5] = f2bf(b.y); u.s[6] = f2bf(b.z); u.s[7] = f2bf(b.w);
  *(uint4*)(out + i) = u.v;
}

// ---------------------------------------------------------------------------
// Router: fp32 (top-k selection must be bit-stable vs reference)
// ---------------------------------------------------------------------------
__global__ __launch_bounds__(256) void router_k(const float* __restrict__ x,
                                                const float* __restrict__ gw,
                                                float* __restrict__ probs,
                                                int* __restrict__ top_e,
                                                float* __restrict__ top_w) {
  const int t = blockIdx.x;
  __shared__ float xs[DM];
  __shared__ float lg[NE];
  __shared__ float ps[NE];
  const int tid = threadIdx.x;

  ((float4*)xs)[tid] = ((const float4*)(x + (size_t)t * DM))[tid];
  __syncthreads();

  const int e = tid >> 3, part = tid & 7;
  const float* w  = gw + (size_t)e * DM + part * 128;
  const float* xv = xs + part * 128;
  float s = 0.f;
#pragma unroll 8
  for (int j = 0; j < 128; j += 4) {
    float4 wv = *(const float4*)(w + j);
    float4 x4 = *(const float4*)(xv + j);
    s = fmaf(wv.x, x4.x, s); s = fmaf(wv.y, x4.y, s);
    s = fmaf(wv.z, x4.z, s); s = fmaf(wv.w, x4.w, s);
  }
  s += __shfl_xor(s, 4); s += __shfl_xor(s, 2); s += __shfl_xor(s, 1);
  if (part == 0) lg[e] = s;
  __syncthreads();

  if (tid < NE) {
    float v = lg[tid];
    float m = v;
    for (int off = 16; off; off >>= 1) m = fmaxf(m, __shfl_xor(m, off));
    float ex = expf(v - m);
    float sum = ex;
    for (int off = 16; off; off >>= 1) sum += __shfl_xor(sum, off);
    float p = ex / sum;
    probs[(size_t)t * NE + tid] = p;
    ps[tid] = p;
  }
  __syncthreads();

  if (tid == 0) {
    int i0 = 0; float v0 = ps[0];
    for (int j = 1; j < NE; ++j) if (ps[j] > v0) { v0 = ps[j]; i0 = j; }
    int i1 = -1; float v1 = -1.f;
    for (int j = 0; j < NE; ++j) {
      if (j == i0) continue;
      if (ps[j] > v1) { v1 = ps[j]; i1 = j; }
    }
    float inv = 1.f / (v0 + v1 + 1e-9f);
    top_e[t * 2]     = i0;  top_e[t * 2 + 1] = i1;
    top_w[t * 2]     = v0 * inv;
    top_w[t * 2 + 1] = v1 * inv;
  }
}

// ---------------------------------------------------------------------------
__global__ __launch_bounds__(256) void probsum_k(const float* __restrict__ probs,
                                                 float* __restrict__ colsum) {
  __shared__ float sd[NE];
  const int tid = threadIdx.x;
  if (tid < NE) sd[tid] = 0.f;
  __syncthreads();
  const int e = tid & 31, rg = tid >> 5;
  size_t t0 = (size_t)blockIdx.x * 256 + (size_t)rg * 32;
  float s = 0.f;
  for (int r = 0; r < 32; ++r) s += probs[(t0 + r) * NE + e];
  atomicAdd(&sd[e], s);
  __syncthreads();
  if (tid < NE) atomicAdd(&colsum[tid], sd[tid]);
}

// ---------------------------------------------------------------------------
// Stable dispatch: per-chunk histogram + ballot ranks (exact argsort order)
// ---------------------------------------------------------------------------
__global__ __launch_bounds__(64) void hist_k(const int* __restrict__ top_e,
                                             int* __restrict__ pos_local,
                                             int* __restrict__ hist) {
  const int lane = threadIdx.x;
  const unsigned long long lt = (1ull << lane) - 1ull;
  int cnt = 0;
  const int base_slot = blockIdx.x * 1024;
  for (int r = 0; r < 16; ++r) {
    int s = base_slot + r * 64 + lane;
    int e = top_e[s];
    int rank = 0;
#pragma unroll
    for (int ex = 0; ex < NE; ++ex) {
      unsigned long long m = __ballot(e == ex);
      int b = __shfl(cnt, ex);
      if (e == ex) rank = b + __popcll(m & lt);
      if (lane == ex) cnt += __popcll(m);
    }
    pos_local[s] = rank;
  }
  if (lane < NE) hist[blockIdx.x * NE + lane] = cnt;
}

__global__ void scan_k(const int* __restrict__ hist,
                       int* __restrict__ chunk_base,
                       int* __restrict__ counts,
                       int* __restrict__ ncap) {
  const int e = threadIdx.x;
  if (e >= NE) return;
  int b = 0;
  for (int c = 0; c < 32; ++c) {
    chunk_base[c * NE + e] = b;
    b += hist[c * NE + e];
  }
  counts[e] = b;
  ncap[e] = b < CAP ? b : CAP;
}

__global__ __launch_bounds__(256) void scatter_k(const int* __restrict__ top_e,
                                                 const float* __restrict__ top_w,
                                                 const int* __restrict__ pos_local,
                                                 const int* __restrict__ chunk_base,
                                                 int* __restrict__ perm,
                                                 float* __restrict__ wgt) {
  const int s = blockIdx.x * 256 + threadIdx.x;
  const int e = top_e[s];
  const int pos = pos_local[s] + chunk_base[(s >> 10) * NE + e];
  if (pos < CAP) {
    perm[e * CAP + pos] = s >> 1;
    wgt[e * CAP + pos]  = top_w[s];
  }
}

__global__ void aux_k(const int* __restrict__ counts,
                      const float* __restrict__ colsum,
                      float* __restrict__ out_aux) {
  const int e = threadIdx.x;
  float v = 0.f;
  if (e < NE) v = ((float)counts[e] / (float)TOK) * (colsum[e] / (float)TOK);
  for (int off = 16; off; off >>= 1) v += __shfl_xor(v, off);
  if (e == 0) out_aux[0] = (float)NE * v;
}

// ---------------------------------------------------------------------------
// FFN1 (bf16 MFMA): act[e,r,j] = silu(x@Wg^T) * (x@Wu^T), 128x64 tile, BK=64.
// 4 waves (2M x 2N); per wave 64 rows x 32 j-cols x {gate,up}.
// LDS: linear dest (global_load_lds) + XOR-swizzled source/read (rule #21):
//   16B slot s of row r holds k-slot (s ^ (r&7)).
// ---------------------------------------------------------------------------
__global__ __launch_bounds__(256) void ffn1_k(const unsigned short* __restrict__ xb,
                                              const unsigned short* __restrict__ wb,
                                              const int* __restrict__ perm,
                                              const int* __restrict__ ncap,
                                              unsigned short* __restrict__ act) {
  const int e  = blockIdx.z;
  const int ne = ncap[e];
  const int rb = blockIdx.y * 128;
  if (rb >= ne) return;
  const int jb = blockIdx.x * 64;

  __shared__ __align__(16) unsigned short As[128 * 64];  // 16KB
  __shared__ __align__(16) unsigned short Bg[64 * 64];   // 8KB
  __shared__ __align__(16) unsigned short Bu[64 * 64];   // 8KB
  __shared__ int perm_s[128];

  const int tid = threadIdx.x;
  const int w = tid >> 6, l = tid & 63;

  if (tid < 128) {
    int r = rb + tid;
    perm_s[tid] = (r < ne) ? perm[e * CAP + r] : perm[e * CAP];  // ne>0 here
  }
  __syncthreads();

  // staging source addresses (pre-swizzled k-slot so LDS dest stays linear)
  const int srow  = l >> 3;              // row within 8-row group
  const int sslot = (l & 7) ^ srow;      // swizzled 16B k-slot
  const unsigned short* srcA[4];
  const unsigned short* srcG[2];
  const unsigned short* srcU[2];
#pragma unroll
  for (int i = 0; i < 4; ++i) {
    int row = (w * 4 + i) * 8 + srow;    // 0..127
    srcA[i] = xb + (size_t)perm_s[row] * DM + sslot * 8;
  }
  const size_t wbase = (size_t)e * (2 * IM) * DM;
#pragma unroll
  for (int i = 0; i < 2; ++i) {
    int row = (w * 2 + i) * 8 + srow;    // 0..63
    srcG[i] = wb + wbase + (size_t)(jb + row) * DM + sslot * 8;
    srcU[i] = wb + wbase + (size_t)(IM + jb + row) * DM + sslot * 8;
  }

  // fragment LDS byte offsets (swizzled read side)
  const int wm = w >> 1, wn = w & 1;
  const int fr = l & 15, kg = l >> 4;
  int offA[4][2], offB[2][2];
#pragma unroll
  for (int mf = 0; mf < 4; ++mf)
#pragma unroll
    for (int h = 0; h < 2; ++h) {
      int row = wm * 64 + mf * 16 + fr;
      offA[mf][h] = row * 128 + (((h * 4 + kg) ^ (row & 7)) * 16);
    }
#pragma unroll
  for (int nf = 0; nf < 2; ++nf)
#pragma unroll
    for (int h = 0; h < 2; ++h) {
      int row = wn * 32 + nf * 16 + fr;
      offB[nf][h] = row * 128 + (((h * 4 + kg) ^ (row & 7)) * 16);
    }

  f32x4 accg[4][2], accu[4][2];
#pragma unroll
  for (int mf = 0; mf < 4; ++mf)
#pragma unroll
    for (int nf = 0; nf < 2; ++nf) {
      accg[mf][nf] = (f32x4){0.f, 0.f, 0.f, 0.f};
      accu[mf][nf] = (f32x4){0.f, 0.f, 0.f, 0.f};
    }

  for (int kt = 0; kt < DM / 64; ++kt) {
    if (kt) __syncthreads();
    const int koff = kt * 64;            // elements
#pragma unroll
    for (int i = 0; i < 4; ++i)
      gload16(srcA[i] + koff, (char*)As + (w * 4 + i) * 1024);
#pragma unroll
    for (int i = 0; i < 2; ++i) {
      gload16(srcG[i] + koff, (char*)Bg + (w * 2 + i) * 1024);
      gload16(srcU[i] + koff, (char*)Bu + (w * 2 + i) * 1024);
    }
    __syncthreads();                     // vmcnt(0)+barrier: tile ready
#pragma unroll
    for (int h = 0; h < 2; ++h) {
      bf16x8 a[4], g[2], u[2];
#pragma unroll
      for (int mf = 0; mf < 4; ++mf)
        a[mf] = *(const bf16x8*)((const char*)As + offA[mf][h]);
#pragma unroll
      for (int nf = 0; nf < 2; ++nf) {
        g[nf] = *(const bf16x8*)((const char*)Bg + offB[nf][h]);
        u[nf] = *(const bf16x8*)((const char*)Bu + offB[nf][h]);
      }
#pragma unroll
      for (int mf = 0; mf < 4; ++mf)
#pragma unroll
        for (int nf = 0; nf < 2; ++nf) {
          accg[mf][nf] = __builtin_amdgcn_mfma_f32_16x16x32_bf16(a[mf], g[nf], accg[mf][nf], 0, 0, 0);
          accu[mf][nf] = __builtin_amdgcn_mfma_f32_16x16x32_bf16(a[mf], u[nf], accu[mf][nf], 0, 0, 0);
        }
    }
  }

  // epilogue: C/D layout col=lane&15, row=(lane>>4)*4+reg  [m89/m91]
  const int orow = (l >> 4) * 4, ocol = l & 15;
#pragma unroll
  for (int mf = 0; mf < 4; ++mf)
#pragma unroll
    for (int nf = 0; nf < 2; ++nf)
#pragma unroll
      for (int r4 = 0; r4 < 4; ++r4) {
        int rloc = wm * 64 + mf * 16 + orow + r4;
        int R = rb + rloc;
        if (R < ne) {
          float gg = accg[mf][nf][r4], uu = accu[mf][nf][r4];
          act[((size_t)e * CAP + R) * IM + jb + wn * 32 + nf * 16 + ocol] =
              f2bf(silu_f(gg) * uu);
        }
      }
}

// ---------------------------------------------------------------------------
// FFN2 (bf16 MFMA) + weighted atomic combine: out[tok] += w*(act@Wd^T).
// 128x128 tile, BK=64; 4 waves (2M x 2N), per wave 64x64.
// ---------------------------------------------------------------------------
__global__ __launch_bounds__(256) void ffn2_k(const unsigned short* __restrict__ actb,
                                              const unsigned short* __restrict__ wb,
                                              const int* __restrict__ perm,
                                              const float* __restrict__ wgt,
                                              const int* __restrict__ ncap,
                                              float* __restrict__ out) {
  const int e  = blockIdx.z;
  const int ne = ncap[e];
  const int rb = blockIdx.y * 128;
  if (rb >= ne) return;
  const int db = blockIdx.x * 128;

  __shared__ __align__(16) unsigned short As[128 * 64];  // 16KB
  __shared__ __align__(16) unsigned short Bs[128 * 64];  // 16KB
  __shared__ int   perm_s[128];
  __shared__ float wgt_s[128];

  const int tid = threadIdx.x;
  const int w = tid >> 6, l = tid & 63;

  if (tid < 128) {
    int r = rb + tid;
    bool v = r < ne;
    perm_s[tid] = v ? perm[e * CAP + r] : 0;
    wgt_s[tid]  = v ? wgt[e * CAP + r] : 0.f;
  }
  __syncthreads();

  const int srow  = l >> 3;
  const int sslot = (l & 7) ^ srow;
  const unsigned short* srcA[4];
  const unsigned short* srcB[4];
#pragma unroll
  for (int i = 0; i < 4; ++i) {
    int row = (w * 4 + i) * 8 + srow;    // 0..127
    srcA[i] = actb + ((size_t)e * CAP + rb + row) * IM + sslot * 8;
    srcB[i] = wb + ((size_t)e * DM + db + row) * IM + sslot * 8;
  }

  const int wm = w >> 1, wn = w & 1;
  const int fr = l & 15, kg = l >> 4;
  int offA[4][2], offB[4][2];
#pragma unroll
  for (int mf = 0; mf < 4; ++mf)
#pragma unroll
    for (int h = 0; h < 2; ++h) {
      int rowA = wm * 64 + mf * 16 + fr;
      int rowB = wn * 64 + mf * 16 + fr;
      offA[mf][h] = rowA * 128 + (((h * 4 + kg) ^ (rowA & 7)) * 16);
      offB[mf][h] = rowB * 128 + (((h * 4 + kg) ^ (rowB & 7)) * 16);
    }

  f32x4 acc[4][4];
#pragma unroll
  for (int mf = 0; mf < 4; ++mf)
#pragma unroll
    for (int nf = 0; nf < 4; ++nf) acc[mf][nf] = (f32x4){0.f, 0.f, 0.f, 0.f};

  for (int kt = 0; kt < IM / 64; ++kt) {
    if (kt) __syncthreads();
    const int koff = kt * 64;
#pragma unroll
    for (int i = 0; i < 4; ++i) {
      gload16(srcA[i] + koff, (char*)As + (w * 4 + i) * 1024);
      gload16(srcB[i] + koff, (char*)Bs + (w * 4 + i) * 1024);
    }
    __syncthreads();
#pragma unroll
    for (int h = 0; h < 2; ++h) {
      bf16x8 a[4], b[4];
#pragma unroll
      for (int mf = 0; mf < 4; ++mf) {
        a[mf] = *(const bf16x8*)((const char*)As + offA[mf][h]);
        b[mf] = *(const bf16x8*)((const char*)Bs + offB[mf][h]);
      }
#pragma unroll
      for (int mf = 0; mf < 4; ++mf)
#pragma unroll
        for (int nf = 0; nf < 4; ++nf)
          acc[mf][nf] = __builtin_amdgcn_mfma_f32_16x16x32_bf16(a[mf], b[nf], acc[mf][nf], 0, 0, 0);
    }
  }

  const int orow = (l >> 4) * 4, ocol = l & 15;
#pragma unroll
  for (int mf = 0; mf < 4; ++mf)
#pragma unroll
    for (int r4 = 0; r4 < 4; ++r4) {
      int rloc = wm * 64 + mf * 16 + orow + r4;
      if (rb + rloc < ne) {
        int token = perm_s[rloc];
        float wt  = wgt_s[rloc];
        float* dst = out + (size_t)token * DM + db + wn * 64 + ocol;
#pragma unroll
        for (int nf = 0; nf < 4; ++nf)
          atomicAdd(dst + nf * 16, wt * acc[mf][nf][r4]);
      }
    }
}

// ---------------------------------------------------------------------------
extern "C" void kernel_launch(void* const* d_in, const int* in_sizes, int n_in,
                              void* d_out, int out_size, void* d_ws, size_t ws_size,
                              hipStream_t stream) {
  const float* x   = (const float*)d_in[0];
  const float* gw  = (const float*)d_in[1];
  const float* wgu = (const float*)d_in[2];
  const float* wdn = (const float*)d_in[3];
  float* out = (float*)d_out;

  char* p = (char*)d_ws;
  auto alloc = [&](size_t bytes) {
    char* r = p;
    p += (bytes + 255) & ~(size_t)255;
    return r;
  };
  float* probs      = (float*)alloc((size_t)TOK * NE * 4);
  int*   top_e      = (int*)  alloc((size_t)NSLOT * 4);
  float* top_w      = (float*)alloc((size_t)NSLOT * 4);
  int*   pos_local  = (int*)  alloc((size_t)NSLOT * 4);
  int*   hist       = (int*)  alloc(32 * NE * 4);
  int*   chunk_base = (int*)  alloc(32 * NE * 4);
  int*   counts     = (int*)  alloc(NE * 4);
  int*   ncapv      = (int*)  alloc(NE * 4);
  float* colsum     = (float*)alloc(NE * 4);
  int*   perm       = (int*)  alloc((size_t)NE * CAP * 4);
  float* wgt        = (float*)alloc((size_t)NE * CAP * 4);
  unsigned short* x_bf   = (unsigned short*)alloc((size_t)TOK * DM * 2);        // 32MB
  unsigned short* act_bf = (unsigned short*)alloc((size_t)NE * CAP * IM * 2);   // 80MB
  unsigned short* wbig   = (unsigned short*)alloc((size_t)NE * 2 * IM * DM * 2);// 128MB
  unsigned short* wgu_bf = wbig;
  unsigned short* wdn_bf = wbig;  // reuses wgu_bf region after ffn1 completes

  zero_k<<<(TOK * DM) / 1024, 256, 0, stream>>>((float4*)out, colsum);
  router_k<<<TOK, 256, 0, stream>>>(x, gw, probs, top_e, top_w);
  probsum_k<<<64, 256, 0, stream>>>(probs, colsum);
  hist_k<<<32, 64, 0, stream>>>(top_e, pos_local, hist);
  scan_k<<<1, 32, 0, stream>>>(hist, chunk_base, counts, ncapv);
  scatter_k<<<NSLOT / 256, 256, 0, stream>>>(top_e, top_w, pos_local, chunk_base,
                                             perm, wgt);
  aux_k<<<1, 64, 0, stream>>>(counts, colsum, out + (size_t)TOK * DM);

  cast_k<<<(TOK * DM) / 2048, 256, 0, stream>>>(x, x_bf);
  cast_k<<<(NE * 2 * IM * DM) / 2048, 256, 0, stream>>>(wgu, wgu_bf);
  ffn1_k<<<dim3(IM / 64, CAP / 128, NE), 256, 0, stream>>>(x_bf, wgu_bf, perm,
                                                           ncapv, act_bf);
  cast_k<<<(NE * DM * IM) / 2048, 256, 0, stream>>>(wdn, wdn_bf);
  ffn2_k<<<dim3(DM / 128, CAP / 128, NE), 256, 0, stream>>>(act_bf, wdn_bf, perm,
                                                            wgt, ncapv, out);
}